// Round 2
// baseline (254.909 us; speedup 1.0000x reference)
//
#include <hip/hip_runtime.h>

#define NROWS 32768
#define DIMS  256
#define KCB   1024

// he2[k] = 0.5 * sum_i embed[k][i]^2   (one wave per codeword)
__global__ __launch_bounds__(64) void he2_kernel(const float* __restrict__ embed,
                                                 float* __restrict__ he2) {
    int k = blockIdx.x;
    int lane = threadIdx.x;
    float4 v = reinterpret_cast<const float4*>(embed + (size_t)k * DIMS)[lane];
    float s = v.x * v.x + v.y * v.y + v.z * v.z + v.w * v.w;
    #pragma unroll
    for (int off = 32; off > 0; off >>= 1) s += __shfl_down(s, off, 64);
    if (lane == 0) he2[k] = 0.5f * s;
}

#define BM   64     // rows per block
#define BN   128    // codes per k-chunk
#define DC   64     // dim chunk
#define LSTR 68     // LDS row stride in floats (272 B: 16B-aligned, bank-spread)

__global__ __launch_bounds__(256, 2) void vq_main(
    const float* __restrict__ x, const float* __restrict__ embed,
    const float* __restrict__ he2,
    float* __restrict__ outq, float* __restrict__ outi)
{
    __shared__ float Xs[BM * LSTR];   // 17408 B
    __shared__ float Es[BN * LSTR];   // 34816 B
    __shared__ int   fIdx[BM];

    const int t  = threadIdx.x;
    const int tx = t & 31;            // col group: cols tx + 32j, j=0..3
    const int ty = t >> 5;            // row group: rows ty + 8i,  i=0..7
    const int rowBase = blockIdx.x * BM;

    float best[8];
    int   bidx[8];
    #pragma unroll
    for (int i = 0; i < 8; ++i) { best[i] = -3.4e38f; bidx[i] = 0; }

    for (int kc = 0; kc < KCB / BN; ++kc) {          // 8 code chunks
        float acc[8][4];
        #pragma unroll
        for (int i = 0; i < 8; ++i)
            #pragma unroll
            for (int j = 0; j < 4; ++j) acc[i][j] = 0.f;

        for (int dc = 0; dc < DIMS / DC; ++dc) {     // 4 dim chunks
            __syncthreads();
            // stage X slice: 64 rows x 64 dims = 1024 float4, 4 per thread
            #pragma unroll
            for (int j = 0; j < 4; ++j) {
                int f = t + 256 * j;
                int r = f >> 4, c4 = f & 15;
                float4 v = *reinterpret_cast<const float4*>(
                    x + (size_t)(rowBase + r) * DIMS + dc * DC + c4 * 4);
                *reinterpret_cast<float4*>(&Xs[r * LSTR + c4 * 4]) = v;
            }
            // stage E slice: 128 rows x 64 dims = 2048 float4, 8 per thread
            #pragma unroll
            for (int j = 0; j < 8; ++j) {
                int f = t + 256 * j;
                int r = f >> 4, c4 = f & 15;
                float4 v = *reinterpret_cast<const float4*>(
                    embed + (size_t)(kc * BN + r) * DIMS + dc * DC + c4 * 4);
                *reinterpret_cast<float4*>(&Es[r * LSTR + c4 * 4]) = v;
            }
            __syncthreads();

            for (int i4 = 0; i4 < DC / 4; ++i4) {
                float4 xf[8], ef[4];
                #pragma unroll
                for (int i = 0; i < 8; ++i)
                    xf[i] = *reinterpret_cast<const float4*>(&Xs[(ty + i * 8) * LSTR + i4 * 4]);
                #pragma unroll
                for (int j = 0; j < 4; ++j)
                    ef[j] = *reinterpret_cast<const float4*>(&Es[(tx + j * 32) * LSTR + i4 * 4]);
                #pragma unroll
                for (int i = 0; i < 8; ++i)
                    #pragma unroll
                    for (int j = 0; j < 4; ++j) {
                        acc[i][j] = fmaf(xf[i].x, ef[j].x, acc[i][j]);
                        acc[i][j] = fmaf(xf[i].y, ef[j].y, acc[i][j]);
                        acc[i][j] = fmaf(xf[i].z, ef[j].z, acc[i][j]);
                        acc[i][j] = fmaf(xf[i].w, ef[j].w, acc[i][j]);
                    }
            }
        }
        // fold this chunk into the running argmax (first-index tie-break)
        #pragma unroll
        for (int j = 0; j < 4; ++j) {
            int c = kc * BN + tx + j * 32;
            float h = he2[c];
            #pragma unroll
            for (int i = 0; i < 8; ++i) {
                float s = acc[i][j] - h;
                if (s > best[i] || (s == best[i] && c < bidx[i])) { best[i] = s; bidx[i] = c; }
            }
        }
    }

    // reduce across the 32 lanes sharing each row (tx spans lanes 0..31 / 32..63)
    #pragma unroll
    for (int i = 0; i < 8; ++i) {
        float b = best[i]; int bi = bidx[i];
        #pragma unroll
        for (int m = 16; m > 0; m >>= 1) {
            float ob = __shfl_xor(b, m, 64);
            int   oi = __shfl_xor(bi, m, 64);
            if (ob > b || (ob == b && oi < bi)) { b = ob; bi = oi; }
        }
        best[i] = b; bidx[i] = bi;
    }
    if (tx == 0) {
        #pragma unroll
        for (int i = 0; i < 8; ++i) fIdx[ty + i * 8] = bidx[i];
    }
    __syncthreads();

    // indices as float32 (exact ints; ref is bf16-rounded for thresholding)
    if (t < BM) outi[rowBase + t] = (float)fIdx[t];

    // fused gather: quantize[r][:] = embed[fIdx[r]][:] as float32
    #pragma unroll
    for (int j = 0; j < 16; ++j) {
        int f = t + 256 * j;
        int r = f >> 6, c4 = f & 63;          // 64 float4 per 256-dim row
        int e = fIdx[r];
        float4 v = *reinterpret_cast<const float4*>(
            embed + (size_t)e * DIMS + c4 * 4);
        *reinterpret_cast<float4*>(outq + (size_t)(rowBase + r) * DIMS + c4 * 4) = v;
    }
}

extern "C" void kernel_launch(void* const* d_in, const int* in_sizes, int n_in,
                              void* d_out, int out_size, void* d_ws, size_t ws_size,
                              hipStream_t stream) {
    const float* x     = (const float*)d_in[0];
    const float* embed = (const float*)d_in[1];
    float* he2 = (float*)d_ws;                 // 1024 floats of scratch
    float* out = (float*)d_out;                // float32 output buffer
    he2_kernel<<<KCB, 64, 0, stream>>>(embed, he2);
    vq_main<<<NROWS / BM, 256, 0, stream>>>(x, embed, he2, out, out + (size_t)NROWS * DIMS);
}

// Round 3
// 105.380 us; speedup vs baseline: 2.4190x; 2.4190x over previous
//
#include <hip/hip_runtime.h>

#define NROWS 32768
#define DIMS  256
#define KCB   1024
#define BM 128
#define BN 128
#define BK 32
#define GY (KCB/BN)   // 8 code-blocks

typedef _Float16 half8 __attribute__((ext_vector_type(8)));
typedef float    f32x4 __attribute__((ext_vector_type(4)));
typedef short    short4v __attribute__((ext_vector_type(4)));

// he2[k] = 0.5 * sum_i embed[k][i]^2
__global__ __launch_bounds__(64) void he2_kernel(const float* __restrict__ embed,
                                                 float* __restrict__ he2) {
    int k = blockIdx.x;
    int lane = threadIdx.x;
    float4 v = reinterpret_cast<const float4*>(embed + (size_t)k * DIMS)[lane];
    float s = v.x * v.x + v.y * v.y + v.z * v.z + v.w * v.w;
    #pragma unroll
    for (int off = 32; off > 0; off >>= 1) s += __shfl_down(s, off, 64);
    if (lane == 0) he2[k] = 0.5f * s;
}

// Fragment-contiguous LDS tiles: [frag(8)][line(64)][8 f16]. Lane l reads
// line l ^ ((l>>4)&3) (read-side swizzle, conflict-free b128); writers place
// (row r, k) at line (((r&15)|(lhi<<4)) ^ lhi), lhi=(k>>3)&3 — spreads one
// row's 4 k-blocks over 4 bank-pairs (write-side conflict-free).
__global__ __launch_bounds__(256, 2) void vq_mfma(
    const float* __restrict__ x, const float* __restrict__ embed,
    const float* __restrict__ he2, float2* __restrict__ part)
{
    __shared__ short XhS[8*64*8], XlS[8*64*8], EhS[8*64*8], ElS[8*64*8];
    __shared__ float sarr[BM*2];
    __shared__ int   iarr[BM*2];

    const int t    = threadIdx.x;
    const int lane = t & 63;
    const int wid  = t >> 6;
    const int wm   = wid >> 1, wn = wid & 1;   // 2x2 wave grid, 64x64 each
    const int rowBase = blockIdx.x * BM;
    const int colBase = blockIdx.y * BN;

    // staging assignment: p=0..3, xi = t + 256p -> r = xi>>3 (0..127), c4 = xi&7
    int soffS[4], xoff[4], eoff[4];
    #pragma unroll
    for (int p = 0; p < 4; ++p) {
        int xi = t + 256 * p;
        int r = xi >> 3, c4 = xi & 7;
        int lhi = (c4 >> 1) & 3;
        int line = ((r & 15) | (lhi << 4)) ^ lhi;
        soffS[p] = (((r >> 4) * 64 + line) << 3) + ((c4 & 1) << 2);  // shorts
        xoff[p] = (rowBase + r) * DIMS + c4 * 4;
        eoff[p] = (colBase + r) * DIMS + c4 * 4;
    }

    f32x4 acc[4][4];
    #pragma unroll
    for (int m = 0; m < 4; ++m)
        #pragma unroll
        for (int n = 0; n < 4; ++n) acc[m][n] = (f32x4){0.f, 0.f, 0.f, 0.f};

    f32x4 xv[4], ev[4];

    // prologue: load + convert + write tile 0
    #pragma unroll
    for (int p = 0; p < 4; ++p) {
        xv[p] = *(const f32x4*)(x + xoff[p]);
        ev[p] = *(const f32x4*)(embed + eoff[p]);
    }
    #pragma unroll
    for (int p = 0; p < 4; ++p) {
        short4v hs, ls, gs, ms;
        #pragma unroll
        for (int e = 0; e < 4; ++e) {
            _Float16 h = (_Float16)xv[p][e];
            _Float16 l = (_Float16)(xv[p][e] - (float)h);
            hs[e] = __builtin_bit_cast(short, h);
            ls[e] = __builtin_bit_cast(short, l);
            _Float16 g = (_Float16)ev[p][e];
            _Float16 q = (_Float16)(ev[p][e] - (float)g);
            gs[e] = __builtin_bit_cast(short, g);
            ms[e] = __builtin_bit_cast(short, q);
        }
        *(short4v*)&XhS[soffS[p]] = hs;  *(short4v*)&XlS[soffS[p]] = ls;
        *(short4v*)&EhS[soffS[p]] = gs;  *(short4v*)&ElS[soffS[p]] = ms;
    }

    const int lsw = lane ^ ((lane >> 4) & 3);
    const half8* XhV = (const half8*)XhS;  const half8* XlV = (const half8*)XlS;
    const half8* EhV = (const half8*)EhS;  const half8* ElV = (const half8*)ElS;

    for (int kk = 0; kk < DIMS / BK; ++kk) {
        __syncthreads();                       // tile kk visible
        if (kk < 7) {
            #pragma unroll
            for (int p = 0; p < 4; ++p) {      // issue next-tile loads early
                xv[p] = *(const f32x4*)(x + xoff[p] + (kk + 1) * BK);
                ev[p] = *(const f32x4*)(embed + eoff[p] + (kk + 1) * BK);
            }
        }
        half8 Ah[4], Al[4], Bh[4], Bl[4];
        #pragma unroll
        for (int m = 0; m < 4; ++m) {
            Ah[m] = XhV[(4 * wm + m) * 64 + lsw];
            Al[m] = XlV[(4 * wm + m) * 64 + lsw];
        }
        #pragma unroll
        for (int n = 0; n < 4; ++n) {
            Bh[n] = EhV[(4 * wn + n) * 64 + lsw];
            Bl[n] = ElV[(4 * wn + n) * 64 + lsw];
        }
        __syncthreads();                       // all waves done reading tile kk
        #pragma unroll
        for (int m = 0; m < 4; ++m)
            #pragma unroll
            for (int n = 0; n < 4; ++n) {
                acc[m][n] = __builtin_amdgcn_mfma_f32_16x16x32_f16(Ah[m], Bh[n], acc[m][n], 0, 0, 0);
                acc[m][n] = __builtin_amdgcn_mfma_f32_16x16x32_f16(Ah[m], Bl[n], acc[m][n], 0, 0, 0);
                acc[m][n] = __builtin_amdgcn_mfma_f32_16x16x32_f16(Al[m], Bh[n], acc[m][n], 0, 0, 0);
            }
        if (kk < 7) {                          // convert + write tile kk+1
            #pragma unroll
            for (int p = 0; p < 4; ++p) {
                short4v hs, ls, gs, ms;
                #pragma unroll
                for (int e = 0; e < 4; ++e) {
                    _Float16 h = (_Float16)xv[p][e];
                    _Float16 l = (_Float16)(xv[p][e] - (float)h);
                    hs[e] = __builtin_bit_cast(short, h);
                    ls[e] = __builtin_bit_cast(short, l);
                    _Float16 g = (_Float16)ev[p][e];
                    _Float16 q = (_Float16)(ev[p][e] - (float)g);
                    gs[e] = __builtin_bit_cast(short, g);
                    ms[e] = __builtin_bit_cast(short, q);
                }
                *(short4v*)&XhS[soffS[p]] = hs;  *(short4v*)&XlS[soffS[p]] = ls;
                *(short4v*)&EhS[soffS[p]] = gs;  *(short4v*)&ElS[soffS[p]] = ms;
            }
        }
    }

    // epilogue: score = acc - he2[col]; per-row argmax (first-index tie-break)
    float h2[4];
    const int c15 = lane & 15;
    #pragma unroll
    for (int n = 0; n < 4; ++n) h2[n] = he2[colBase + 64 * wn + 16 * n + c15];
    const int colg0 = colBase + 64 * wn + c15;

    #pragma unroll
    for (int m = 0; m < 4; ++m) {
        #pragma unroll
        for (int reg = 0; reg < 4; ++reg) {
            float b = acc[m][0][reg] - h2[0];
            int bi = colg0;
            #pragma unroll
            for (int n = 1; n < 4; ++n) {
                float s = acc[m][n][reg] - h2[n];
                int c = colg0 + 16 * n;
                if (s > b) { b = s; bi = c; }
            }
            #pragma unroll
            for (int msk = 1; msk <= 8; msk <<= 1) {
                float ob = __shfl_xor(b, msk, 64);
                int   oi = __shfl_xor(bi, msk, 64);
                if (ob > b || (ob == b && oi < bi)) { b = ob; bi = oi; }
            }
            if (c15 == 0) {
                int row = 64 * wm + 16 * m + 4 * (lane >> 4) + reg;
                sarr[row * 2 + wn] = b;
                iarr[row * 2 + wn] = bi;
            }
        }
    }
    __syncthreads();
    if (t < BM) {
        float s0 = sarr[t * 2], s1 = sarr[t * 2 + 1];
        int   i0 = iarr[t * 2], i1 = iarr[t * 2 + 1];
        float bs = s0; int bi = i0;
        if (s1 > bs) { bs = s1; bi = i1; }     // i0 < i1 always: ties keep i0
        part[(size_t)(rowBase + t) * GY + blockIdx.y] =
            make_float2(bs, __int_as_float(bi));
    }
}

// combine the 8 code-block partials per row, write index + gather embed row
__global__ __launch_bounds__(256) void vq_combine(
    const float2* __restrict__ part, const float* __restrict__ embed,
    float* __restrict__ outq, float* __restrict__ outi)
{
    __shared__ int idxS[256];
    const int t = threadIdx.x;
    const int rowBase = blockIdx.x * 256;
    const int row = rowBase + t;

    float2 p0 = part[(size_t)row * GY];
    float bs = p0.x; int bi = __float_as_int(p0.y);
    #pragma unroll
    for (int g = 1; g < GY; ++g) {
        float2 p = part[(size_t)row * GY + g];
        int i = __float_as_int(p.y);
        if (p.x > bs || (p.x == bs && i < bi)) { bs = p.x; bi = i; }
    }
    idxS[t] = bi;
    outi[row] = (float)bi;
    __syncthreads();

    #pragma unroll 4
    for (int q = 0; q < 64; ++q) {
        int f = t + 256 * q;
        int r = f >> 6, c4 = f & 63;
        int e = idxS[r];
        f32x4 v = *(const f32x4*)(embed + (size_t)e * DIMS + c4 * 4);
        *(f32x4*)(outq + (size_t)(rowBase + r) * DIMS + c4 * 4) = v;
    }
}

extern "C" void kernel_launch(void* const* d_in, const int* in_sizes, int n_in,
                              void* d_out, int out_size, void* d_ws, size_t ws_size,
                              hipStream_t stream) {
    const float* x     = (const float*)d_in[0];
    const float* embed = (const float*)d_in[1];
    float*  he2  = (float*)d_ws;                          // 4 KB
    float2* part = (float2*)((char*)d_ws + 8192);         // 2 MB partials
    float*  out  = (float*)d_out;
    he2_kernel<<<KCB, 64, 0, stream>>>(embed, he2);
    vq_mfma<<<dim3(NROWS / BM, GY), 256, 0, stream>>>(x, embed, he2, part);
    vq_combine<<<NROWS / 256, 256, 0, stream>>>(part, embed, out, out + (size_t)NROWS * DIMS);
}

// Round 5
// 101.460 us; speedup vs baseline: 2.5124x; 1.0386x over previous
//
#include <hip/hip_runtime.h>
#include <stdint.h>

#define NROWS 32768
#define DIMS  256
#define KCB   1024
#define BM 128
#define BN 128
#define GY (KCB/BN)   // 8 code-blocks

typedef _Float16 half8   __attribute__((ext_vector_type(8)));
typedef float    f32x4   __attribute__((ext_vector_type(4)));
typedef short    short4v __attribute__((ext_vector_type(4)));
typedef short    short8v __attribute__((ext_vector_type(8)));

// async global->LDS, 16B per lane; LDS dest = uniform base + lane*16
__device__ __forceinline__ void gload_lds16(const void* g, void* l) {
    __builtin_amdgcn_global_load_lds(
        (const __attribute__((address_space(1))) uint32_t*)g,
        (__attribute__((address_space(3))) uint32_t*)l, 16, 0, 0);
}

__device__ __forceinline__ short2 f16split(float v) {
    _Float16 hh = (_Float16)v;
    _Float16 ll = (_Float16)(v - (float)hh);
    return make_short2(__builtin_bit_cast(short, hh),
                       __builtin_bit_cast(short, ll));
}

// ---------------- splitter: X -> fragment-ordered f16 h/l planes ----------
// Xp layout (shorts): frag(G=row-group of 16, c=k-chunk of 32, hl) is 1KB:
//   lane l holds row G*16+(l&15), k = c*32+(l>>4)*8 .. +7
//   short index = G*8192 + c*1024 + hl*512 + l*8
__global__ __launch_bounds__(256) void xsplit(const float* __restrict__ x,
                                              short* __restrict__ Xp) {
    int T = blockIdx.x * 256 + threadIdx.x;
    int l = T & 63, c = (T >> 6) & 7, G = T >> 9;
    int row = G * 16 + (l & 15);
    int kb  = c * 32 + (l >> 4) * 8;
    const f32x4* src = (const f32x4*)(x + (size_t)row * DIMS + kb);
    f32x4 a = src[0], b = src[1];
    short8v h, lo;
    #pragma unroll
    for (int e = 0; e < 4; ++e) { short2 r = f16split(a[e]); h[e] = r.x; lo[e] = r.y; }
    #pragma unroll
    for (int e = 0; e < 4; ++e) { short2 r = f16split(b[e]); h[4 + e] = r.x; lo[4 + e] = r.y; }
    size_t base = (size_t)G * 8192 + c * 1024 + l * 8;
    *(short8v*)(Xp + base)       = h;
    *(short8v*)(Xp + base + 512) = lo;
}

// ---------------- splitter: E (same layout, cols as rows) + he2 -----------
__global__ __launch_bounds__(256) void esplit(const float* __restrict__ embed,
                                              short* __restrict__ Ep,
                                              float* __restrict__ he2) {
    int r = blockIdx.x * 4 + (threadIdx.x >> 6);   // code row 0..1023
    int l = threadIdx.x & 63;
    f32x4 v = ((const f32x4*)(embed + (size_t)r * DIMS))[l];
    float s = v[0]*v[0] + v[1]*v[1] + v[2]*v[2] + v[3]*v[3];
    #pragma unroll
    for (int off = 32; off > 0; off >>= 1) s += __shfl_down(s, off, 64);
    if (l == 0) he2[r] = 0.5f * s;
    // 4 elems at k = l*4
    int G = r >> 4, cc = l >> 3;
    int fl = (r & 15) + 16 * ((l >> 1) & 3);
    size_t base = (size_t)G * 8192 + cc * 1024 + fl * 8 + (l & 1) * 4;
    short4v h, lo;
    #pragma unroll
    for (int e = 0; e < 4; ++e) { short2 q = f16split(v[e]); h[e] = q.x; lo[e] = q.y; }
    *(short4v*)(Ep + base)       = h;
    *(short4v*)(Ep + base + 512) = lo;
}

// ---------------- main GEMM+argmax, pre-split inputs, gload_lds -----------
#define LDSBUF 32768   // one tile: X frags 16KB + E frags 16KB
__global__ __launch_bounds__(256, 2) void vq_mfma(
    const short* __restrict__ Xp, const short* __restrict__ Ep,
    const float* __restrict__ he2, float2* __restrict__ part)
{
    __shared__ char  lds[2 * LDSBUF];
    __shared__ float sarr[BM * 2];
    __shared__ int   iarr[BM * 2];

    const int t = threadIdx.x, lane = t & 63, w = t >> 6;
    const int wm = w >> 1, wn = w & 1;
    // XCD-swizzle: all 8 code-blocks of a row-panel on one XCD
    const int sid = blockIdx.x;
    const int xcd = sid & 7, j = sid >> 3;
    const int rb = xcd * 32 + (j >> 3), cb = j & 7;
    const int rowBase = rb * BM, colBase = cb * BN;

    // staging: wave w owns fragments f = 8w..8w+7 (f<16: X, else E)
    const char* gbase[8];
    int ldsoff[8];
    #pragma unroll
    for (int p = 0; p < 8; ++p) {
        int f = w * 8 + p;
        ldsoff[p] = f * 1024;
        const char* b;
        if (f < 16) b = (const char*)Xp + ((size_t)(rb * 8 + (f >> 1)) * 16 + (f & 1)) * 1024;
        else        b = (const char*)Ep + ((size_t)(cb * 8 + ((f - 16) >> 1)) * 16 + ((f - 16) & 1)) * 1024;
        gbase[p] = b + lane * 16;
    }

    f32x4 acc[4][4];
    #pragma unroll
    for (int m = 0; m < 4; ++m)
        #pragma unroll
        for (int n = 0; n < 4; ++n) acc[m][n] = (f32x4){0.f, 0.f, 0.f, 0.f};

    // prologue: stage tile 0 into buf0
    #pragma unroll
    for (int p = 0; p < 8; ++p) gload_lds16(gbase[p], lds + ldsoff[p]);

    #pragma unroll
    for (int c = 0; c < 8; ++c) {
        __syncthreads();                       // drains vmcnt: tile c resident
        if (c < 7) {
            #pragma unroll
            for (int p = 0; p < 8; ++p)
                gload_lds16(gbase[p] + (c + 1) * 2048,
                            lds + ((c + 1) & 1) * LDSBUF + ldsoff[p]);
        }
        const char* B = lds + (c & 1) * LDSBUF;
        half8 Ah[4], Al[4], Bh[4], Bl[4];
        #pragma unroll
        for (int m = 0; m < 4; ++m) {
            Ah[m] = *(const half8*)(B + ((wm * 4 + m) * 2) * 1024 + lane * 16);
            Al[m] = *(const half8*)(B + ((wm * 4 + m) * 2 + 1) * 1024 + lane * 16);
        }
        #pragma unroll
        for (int n = 0; n < 4; ++n) {
            Bh[n] = *(const half8*)(B + 16384 + ((wn * 4 + n) * 2) * 1024 + lane * 16);
            Bl[n] = *(const half8*)(B + 16384 + ((wn * 4 + n) * 2 + 1) * 1024 + lane * 16);
        }
        #pragma unroll
        for (int m = 0; m < 4; ++m)
            #pragma unroll
            for (int n = 0; n < 4; ++n) {
                acc[m][n] = __builtin_amdgcn_mfma_f32_16x16x32_f16(Ah[m], Bh[n], acc[m][n], 0, 0, 0);
                acc[m][n] = __builtin_amdgcn_mfma_f32_16x16x32_f16(Ah[m], Bl[n], acc[m][n], 0, 0, 0);
                acc[m][n] = __builtin_amdgcn_mfma_f32_16x16x32_f16(Al[m], Bh[n], acc[m][n], 0, 0, 0);
            }
    }

    // epilogue: score = acc - he2[col]; per-row argmax (verified round 3)
    float h2[4];
    const int c15 = lane & 15;
    #pragma unroll
    for (int n = 0; n < 4; ++n) h2[n] = he2[colBase + 64 * wn + 16 * n + c15];
    const int colg0 = colBase + 64 * wn + c15;

    #pragma unroll
    for (int m = 0; m < 4; ++m) {
        #pragma unroll
        for (int reg = 0; reg < 4; ++reg) {
            float b = acc[m][0][reg] - h2[0];
            int bi = colg0;
            #pragma unroll
            for (int n = 1; n < 4; ++n) {
                float s = acc[m][n][reg] - h2[n];
                int c = colg0 + 16 * n;
                if (s > b) { b = s; bi = c; }
            }
            #pragma unroll
            for (int msk = 1; msk <= 8; msk <<= 1) {
                float ob = __shfl_xor(b, msk, 64);
                int   oi = __shfl_xor(bi, msk, 64);
                if (ob > b || (ob == b && oi < bi)) { b = ob; bi = oi; }
            }
            if (c15 == 0) {
                int row = 64 * wm + 16 * m + 4 * (lane >> 4) + reg;
                sarr[row * 2 + wn] = b;
                iarr[row * 2 + wn] = bi;
            }
        }
    }
    __syncthreads();
    if (t < BM) {
        float s0 = sarr[t * 2], s1 = sarr[t * 2 + 1];
        int   i0 = iarr[t * 2], i1 = iarr[t * 2 + 1];
        float bs = s0; int bi = i0;
        if (s1 > bs) { bs = s1; bi = i1; }     // i0 < i1: ties keep i0
        part[(size_t)(rowBase + t) * GY + cb] = make_float2(bs, __int_as_float(bi));
    }
}

// ---------------- combine partials + gather ----------------
__global__ __launch_bounds__(256) void vq_combine(
    const float2* __restrict__ part, const float* __restrict__ embed,
    float* __restrict__ outq, float* __restrict__ outi)
{
    __shared__ int idxS[256];
    const int t = threadIdx.x;
    const int rowBase = blockIdx.x * 256;
    const int row = rowBase + t;

    float2 p0 = part[(size_t)row * GY];
    float bs = p0.x; int bi = __float_as_int(p0.y);
    #pragma unroll
    for (int g = 1; g < GY; ++g) {
        float2 p = part[(size_t)row * GY + g];
        int i = __float_as_int(p.y);
        if (p.x > bs || (p.x == bs && i < bi)) { bs = p.x; bi = i; }
    }
    idxS[t] = bi;
    outi[row] = (float)bi;
    __syncthreads();

    #pragma unroll 4
    for (int q = 0; q < 64; ++q) {
        int f = t + 256 * q;
        int r = f >> 6, c4 = f & 63;
        int e = idxS[r];
        f32x4 v = *(const f32x4*)(embed + (size_t)e * DIMS + c4 * 4);
        *(f32x4*)(outq + (size_t)(rowBase + r) * DIMS + c4 * 4) = v;
    }
}

// ================= legacy (round-3, verified) fallback ====================
__global__ __launch_bounds__(64) void he2_kernel(const float* __restrict__ embed,
                                                 float* __restrict__ he2) {
    int k = blockIdx.x;
    int lane = threadIdx.x;
    float4 v = reinterpret_cast<const float4*>(embed + (size_t)k * DIMS)[lane];
    float s = v.x * v.x + v.y * v.y + v.z * v.z + v.w * v.w;
    #pragma unroll
    for (int off = 32; off > 0; off >>= 1) s += __shfl_down(s, off, 64);
    if (lane == 0) he2[k] = 0.5f * s;
}

__global__ __launch_bounds__(256, 2) void vq_mfma_legacy(
    const float* __restrict__ x, const float* __restrict__ embed,
    const float* __restrict__ he2, float2* __restrict__ part)
{
    __shared__ short XhS[8*64*8], XlS[8*64*8], EhS[8*64*8], ElS[8*64*8];
    __shared__ float sarr[BM*2];
    __shared__ int   iarr[BM*2];

    const int t    = threadIdx.x;
    const int lane = t & 63;
    const int wid  = t >> 6;
    const int wm   = wid >> 1, wn = wid & 1;
    const int rowBase = blockIdx.x * BM;
    const int colBase = blockIdx.y * BN;

    int soffS[4], xoff[4], eoff[4];
    #pragma unroll
    for (int p = 0; p < 4; ++p) {
        int xi = t + 256 * p;
        int r = xi >> 3, c4 = xi & 7;
        int lhi = (c4 >> 1) & 3;
        int line = ((r & 15) | (lhi << 4)) ^ lhi;
        soffS[p] = (((r >> 4) * 64 + line) << 3) + ((c4 & 1) << 2);
        xoff[p] = (rowBase + r) * DIMS + c4 * 4;
        eoff[p] = (colBase + r) * DIMS + c4 * 4;
    }

    f32x4 acc[4][4];
    #pragma unroll
    for (int m = 0; m < 4; ++m)
        #pragma unroll
        for (int n = 0; n < 4; ++n) acc[m][n] = (f32x4){0.f, 0.f, 0.f, 0.f};

    f32x4 xv[4], ev[4];
    #pragma unroll
    for (int p = 0; p < 4; ++p) {
        xv[p] = *(const f32x4*)(x + xoff[p]);
        ev[p] = *(const f32x4*)(embed + eoff[p]);
    }
    #pragma unroll
    for (int p = 0; p < 4; ++p) {
        short4v hs, ls, gs, ms;
        #pragma unroll
        for (int e = 0; e < 4; ++e) {
            short2 r1 = f16split(xv[p][e]); hs[e] = r1.x; ls[e] = r1.y;
            short2 r2 = f16split(ev[p][e]); gs[e] = r2.x; ms[e] = r2.y;
        }
        *(short4v*)&XhS[soffS[p]] = hs;  *(short4v*)&XlS[soffS[p]] = ls;
        *(short4v*)&EhS[soffS[p]] = gs;  *(short4v*)&ElS[soffS[p]] = ms;
    }

    const int lsw = lane ^ ((lane >> 4) & 3);
    const half8* XhV = (const half8*)XhS;  const half8* XlV = (const half8*)XlS;
    const half8* EhV = (const half8*)EhS;  const half8* ElV = (const half8*)ElS;

    for (int kk = 0; kk < DIMS / 32; ++kk) {
        __syncthreads();
        if (kk < 7) {
            #pragma unroll
            for (int p = 0; p < 4; ++p) {
                xv[p] = *(const f32x4*)(x + xoff[p] + (kk + 1) * 32);
                ev[p] = *(const f32x4*)(embed + eoff[p] + (kk + 1) * 32);
            }
        }
        half8 Ah[4], Al[4], Bh[4], Bl[4];
        #pragma unroll
        for (int m = 0; m < 4; ++m) {
            Ah[m] = XhV[(4 * wm + m) * 64 + lsw];
            Al[m] = XlV[(4 * wm + m) * 64 + lsw];
        }
        #pragma unroll
        for (int n = 0; n < 4; ++n) {
            Bh[n] = EhV[(4 * wn + n) * 64 + lsw];
            Bl[n] = ElV[(4 * wn + n) * 64 + lsw];
        }
        __syncthreads();
        #pragma unroll
        for (int m = 0; m < 4; ++m)
            #pragma unroll
            for (int n = 0; n < 4; ++n) {
                acc[m][n] = __builtin_amdgcn_mfma_f32_16x16x32_f16(Ah[m], Bh[n], acc[m][n], 0, 0, 0);
                acc[m][n] = __builtin_amdgcn_mfma_f32_16x16x32_f16(Ah[m], Bl[n], acc[m][n], 0, 0, 0);
                acc[m][n] = __builtin_amdgcn_mfma_f32_16x16x32_f16(Al[m], Bh[n], acc[m][n], 0, 0, 0);
            }
        if (kk < 7) {
            #pragma unroll
            for (int p = 0; p < 4; ++p) {
                short4v hs, ls, gs, ms;
                #pragma unroll
                for (int e = 0; e < 4; ++e) {
                    short2 r1 = f16split(xv[p][e]); hs[e] = r1.x; ls[e] = r1.y;
                    short2 r2 = f16split(ev[p][e]); gs[e] = r2.x; ms[e] = r2.y;
                }
                *(short4v*)&XhS[soffS[p]] = hs;  *(short4v*)&XlS[soffS[p]] = ls;
                *(short4v*)&EhS[soffS[p]] = gs;  *(short4v*)&ElS[soffS[p]] = ms;
            }
        }
    }

    float h2[4];
    const int c15 = lane & 15;
    #pragma unroll
    for (int n = 0; n < 4; ++n) h2[n] = he2[colBase + 64 * wn + 16 * n + c15];
    const int colg0 = colBase + 64 * wn + c15;

    #pragma unroll
    for (int m = 0; m < 4; ++m) {
        #pragma unroll
        for (int reg = 0; reg < 4; ++reg) {
            float b = acc[m][0][reg] - h2[0];
            int bi = colg0;
            #pragma unroll
            for (int n = 1; n < 4; ++n) {
                float s = acc[m][n][reg] - h2[n];
                int c = colg0 + 16 * n;
                if (s > b) { b = s; bi = c; }
            }
            #pragma unroll
            for (int msk = 1; msk <= 8; msk <<= 1) {
                float ob = __shfl_xor(b, msk, 64);
                int   oi = __shfl_xor(bi, msk, 64);
                if (ob > b || (ob == b && oi < bi)) { b = ob; bi = oi; }
            }
            if (c15 == 0) {
                int row = 64 * wm + 16 * m + 4 * (lane >> 4) + reg;
                sarr[row * 2 + wn] = b;
                iarr[row * 2 + wn] = bi;
            }
        }
    }
    __syncthreads();
    if (t < BM) {
        float s0 = sarr[t * 2], s1 = sarr[t * 2 + 1];
        int   i0 = iarr[t * 2], i1 = iarr[t * 2 + 1];
        float bs = s0; int bi = i0;
        if (s1 > bs) { bs = s1; bi = i1; }
        part[(size_t)(rowBase + t) * GY + blockIdx.y] = make_float2(bs, __int_as_float(bi));
    }
}

extern "C" void kernel_launch(void* const* d_in, const int* in_sizes, int n_in,
                              void* d_out, int out_size, void* d_ws, size_t ws_size,
                              hipStream_t stream) {
    const float* x     = (const float*)d_in[0];
    const float* embed = (const float*)d_in[1];
    float*  he2  = (float*)d_ws;                          // 4 KB (+pad)
    float2* part = (float2*)((char*)d_ws + 8192);         // 2 MB
    short*  Xp   = (short*)((char*)d_ws + 8192 + 2097152);        // 32 MB
    short*  Ep   = (short*)((char*)d_ws + 8192 + 2097152 + 33554432); // 1 MB
    float*  out  = (float*)d_out;
    const size_t needed = 8192 + 2097152 + 33554432 + 1048576;

    if (ws_size >= needed) {
        xsplit<<<4096, 256, 0, stream>>>(x, Xp);
        esplit<<<256, 256, 0, stream>>>(embed, Ep, he2);
        vq_mfma<<<(NROWS / BM) * GY, 256, 0, stream>>>(Xp, Ep, he2, part);
    } else {
        he2_kernel<<<KCB, 64, 0, stream>>>(embed, he2);
        vq_mfma_legacy<<<dim3(NROWS / BM, GY), 256, 0, stream>>>(x, embed, he2, part);
    }
    vq_combine<<<NROWS / 256, 256, 0, stream>>>(part, embed, out, out + (size_t)NROWS * DIMS);
}